// Round 5
// baseline (1831.507 us; speedup 1.0000x reference)
//
#include <hip/hip_runtime.h>
#include <cstdint>
#include <cfloat>
#include <cmath>

typedef unsigned short ushort_t;
typedef short bf16x8 __attribute__((ext_vector_type(8)));
typedef float f32x4 __attribute__((ext_vector_type(4)));

__device__ inline ushort_t f2bf(float f) {
    union { float f; unsigned u; } v; v.f = f;
    return (ushort_t)((v.u + 0x7fffu + ((v.u >> 16) & 1u)) >> 16);   // RNE
}
__device__ inline float bf2f(ushort_t u) {
    union { unsigned u; float f; } v; v.u = ((unsigned)u) << 16;
    return v.f;
}
__device__ inline float bflo_f(unsigned w) { union { unsigned u; float f; } v; v.u = w << 16; return v.f; }
__device__ inline float bfhi_f(unsigned w) { union { unsigned u; float f; } v; v.u = w & 0xFFFF0000u; return v.f; }
__device__ inline unsigned pk2(float a, float b) {
    return (unsigned)f2bf(a) | ((unsigned)f2bf(b) << 16);
}
__device__ inline unsigned relu2(unsigned p) {
    unsigned lo = (p & 0x8000u) ? 0u : (p & 0xFFFFu);
    unsigned hi = (p & 0x80000000u) ? 0u : (p & 0xFFFF0000u);
    return lo | hi;
}

// ---------------------------------------------------------------------------
// Weight prepack: fp32 OIHW -> bf16 [pos=ky*3+kx][co][cip] with cip padded to 32
// ---------------------------------------------------------------------------
struct PPJob { const float* src; ushort_t* dst; int ci; int co; };
struct PPArgs { PPJob j[15]; };

__global__ __launch_bounds__(256) void prepack_k(PPArgs a) {
    const PPJob p = a.j[blockIdx.x];
    const int tot = 9 * p.co * 32;
    for (int i = threadIdx.x; i < tot; i += 256) {
        const int cip = i & 31;
        const int rest = i >> 5;
        const int co = rest % p.co;
        const int pos = rest / p.co;
        float v = 0.f;
        if (cip < p.ci) v = p.src[(co * p.ci + cip) * 9 + pos];
        p.dst[i] = f2bf(v);
    }
}

// ---------------------------------------------------------------------------
// FUSED resblock: out = x + conv2(relu(conv1(relu(x)))), both convs 3x3 pad 1.
// 16x16 output tile/block, 256 thr. conv1 computed on 18x18 halo region
// (rows: 4 waves x 5 rows clamped; cols: 2 overlapping 16-wide MFMA groups),
// parked relu'd in LDS t2; conv2 consumes it. Image-OOB conv1 pixels -> 0.
// MFMA A=weights(16 co x t), B=input pixels; K=32 ci zero-padded in weights.
// ---------------------------------------------------------------------------
template<int C>
__global__ __launch_bounds__(256) void resblock_k(
    const ushort_t* __restrict__ x, const ushort_t* __restrict__ wp1,
    const ushort_t* __restrict__ wp2, const float* __restrict__ b1,
    const float* __restrict__ b2, ushort_t* __restrict__ out, int H, int TX)
{
    constexpr int NT = C / 16;
    __shared__ __align__(16) ushort_t tin[20 * 20 * 40];   // relu(x), origin (-2,-2)
    __shared__ __align__(16) ushort_t t2[18 * 18 * 40];    // relu(conv1), origin (-1,-1)

    const int n = blockIdx.y, tile = blockIdx.x;
    const int ty0 = (tile / TX) * 16, tx0 = (tile % TX) * 16;
    const int tid = threadIdx.x, lane = tid & 63, wv = tid >> 6;
    const int col = lane & 15, oct = lane >> 4;

    // ---- stage relu(x): 20x20 halo, zero OOB, all 32 ch slots written ----
    for (int i = tid; i < 400 * 4; i += 256) {
        const int px = i >> 2, oc = i & 3;
        const int r = px / 20, c = px % 20;
        const int gy = ty0 - 2 + r, gx = tx0 - 2 + c;
        uint4 v = make_uint4(0, 0, 0, 0);
        if (oc * 8 < C && (unsigned)gy < (unsigned)H && (unsigned)gx < (unsigned)H) {
            v = *(const uint4*)&x[(((size_t)n * H + gy) * H + gx) * C + oc * 8];
            v.x = relu2(v.x); v.y = relu2(v.y); v.z = relu2(v.z); v.w = relu2(v.w);
        }
        *(uint4*)&tin[px * 40 + oc * 8] = v;
    }

    bf16x8 wf[9][NT];
    #pragma unroll
    for (int p = 0; p < 9; ++p)
        #pragma unroll
        for (int t = 0; t < NT; ++t)
            wf[p][t] = *(const bf16x8*)&wp1[(p * C + t * 16 + col) * 32 + oct * 8];
    __syncthreads();

    // ---- conv1 on rows -1..16, cols -1..16; relu+bias -> t2 ----
    #pragma unroll
    for (int rr = 0; rr < 5; ++rr) {
        int r1 = wv * 5 + rr - 1;
        if (r1 > 16) r1 = 16;                 // clamped duplicates are benign
        #pragma unroll
        for (int g = 0; g < 2; ++g) {
            const int pc = col + (g ? 1 : -1);
            f32x4 acc[NT];
            #pragma unroll
            for (int t = 0; t < NT; ++t) acc[t] = (f32x4){0.f, 0.f, 0.f, 0.f};
            #pragma unroll
            for (int p = 0; p < 9; ++p) {
                const int ky = p / 3, kx = p % 3;
                const bf16x8 b = *(const bf16x8*)&tin[((r1 + ky + 1) * 20 + (pc + kx + 1)) * 40 + oct * 8];
                #pragma unroll
                for (int t = 0; t < NT; ++t)
                    acc[t] = __builtin_amdgcn_mfma_f32_16x16x32_bf16(wf[p][t], b, acc[t], 0, 0, 0);
            }
            const bool valid = (unsigned)(ty0 + r1) < (unsigned)H && (unsigned)(tx0 + pc) < (unsigned)H;
            const int pbase = ((r1 + 1) * 18 + (pc + 1)) * 40;
            #pragma unroll
            for (int t = 0; t < NT; ++t) {
                const float4 bb = *(const float4*)&b1[t * 16 + oct * 4];
                uint2 o = make_uint2(0, 0);
                if (valid) {
                    o.x = pk2(fmaxf(acc[t][0] + bb.x, 0.f), fmaxf(acc[t][1] + bb.y, 0.f));
                    o.y = pk2(fmaxf(acc[t][2] + bb.z, 0.f), fmaxf(acc[t][3] + bb.w, 0.f));
                }
                *(uint2*)&t2[pbase + t * 16 + oct * 4] = o;
            }
            if constexpr (C == 16)             // clean K-slots 16..31 for conv2
                *(uint2*)&t2[pbase + 16 + oct * 4] = make_uint2(0, 0);
        }
    }
    __syncthreads();

    // ---- conv2 on 16x16 tile, + bias2 + skip(x), store ----
    #pragma unroll
    for (int p = 0; p < 9; ++p)
        #pragma unroll
        for (int t = 0; t < NT; ++t)
            wf[p][t] = *(const bf16x8*)&wp2[(p * C + t * 16 + col) * 32 + oct * 8];

    f32x4 acc2[4][NT];
    #pragma unroll
    for (int r = 0; r < 4; ++r)
        #pragma unroll
        for (int t = 0; t < NT; ++t) acc2[r][t] = (f32x4){0.f, 0.f, 0.f, 0.f};

    #pragma unroll
    for (int p = 0; p < 9; ++p) {
        const int ky = p / 3, kx = p % 3;
        #pragma unroll
        for (int r = 0; r < 4; ++r) {
            const int r2 = wv * 4 + r;
            const bf16x8 b = *(const bf16x8*)&t2[((r2 + ky) * 18 + (col + kx)) * 40 + oct * 8];
            #pragma unroll
            for (int t = 0; t < NT; ++t)
                acc2[r][t] = __builtin_amdgcn_mfma_f32_16x16x32_bf16(wf[p][t], b, acc2[r][t], 0, 0, 0);
        }
    }

    #pragma unroll
    for (int r = 0; r < 4; ++r) {
        const int gy = ty0 + wv * 4 + r, gx = tx0 + col;
        const size_t pbase = (((size_t)n * H + gy) * H + gx) * C + oct * 4;
        #pragma unroll
        for (int t = 0; t < NT; ++t) {
            const float4 bb = *(const float4*)&b2[t * 16 + oct * 4];
            const uint2 s = *(const uint2*)&x[pbase + t * 16];
            uint2 o;
            o.x = pk2(acc2[r][t][0] + bb.x + bflo_f(s.x), acc2[r][t][1] + bb.y + bfhi_f(s.x));
            o.y = pk2(acc2[r][t][2] + bb.z + bflo_f(s.y), acc2[r][t][3] + bb.w + bfhi_f(s.y));
            *(uint2*)&out[pbase + t * 16] = o;
        }
    }
}

// ---------------------------------------------------------------------------
// FUSED entry conv + maxpool(3x3,s2,pad1): out = pool(conv(x)+bias).
// Conv computed on 17x17 halo region (OOB pixels -> bf16 -inf = pool identity),
// pooled 8x8xCO per block straight out of LDS. NCHWIN: fp32 NCHW input (s0).
// ---------------------------------------------------------------------------
template<int CIR, int CO, bool NCHWIN>
__global__ __launch_bounds__(256) void convpool_k(
    const void* __restrict__ inv, const ushort_t* __restrict__ wp,
    const float* __restrict__ bias, ushort_t* __restrict__ out, int H, int TX)
{
    constexpr int NT = CO / 16;
    __shared__ __align__(16) ushort_t tin[20 * 20 * 40];
    __shared__ __align__(16) ushort_t t2[18 * 18 * 40];

    const int n = blockIdx.y, tile = blockIdx.x;
    const int ty0 = (tile / TX) * 16, tx0 = (tile % TX) * 16;
    const int tid = threadIdx.x, lane = tid & 63, wv = tid >> 6;
    const int col = lane & 15, oct = lane >> 4;

    // ---- stage input 20x20 halo ----
    if constexpr (NCHWIN) {
        for (int i = tid; i < 2000; i += 256)
            *(uint4*)&tin[i * 8] = make_uint4(0, 0, 0, 0);
        __syncthreads();
        const float* gin = (const float*)inv;
        #pragma unroll
        for (int ci = 0; ci < CIR; ++ci) {
            for (int px = tid; px < 400; px += 256) {
                const int r = px / 20, c = px % 20;
                const int gy = ty0 - 2 + r, gx = tx0 - 2 + c;
                if ((unsigned)gy < (unsigned)H && (unsigned)gx < (unsigned)H)
                    tin[px * 40 + ci] = f2bf(gin[(((size_t)n * CIR + ci) * H + gy) * H + gx]);
            }
        }
    } else {
        const ushort_t* gin = (const ushort_t*)inv;
        for (int i = tid; i < 400 * 4; i += 256) {
            const int px = i >> 2, oc = i & 3;
            const int r = px / 20, c = px % 20;
            const int gy = ty0 - 2 + r, gx = tx0 - 2 + c;
            uint4 v = make_uint4(0, 0, 0, 0);
            if (oc * 8 < CIR && (unsigned)gy < (unsigned)H && (unsigned)gx < (unsigned)H)
                v = *(const uint4*)&gin[(((size_t)n * H + gy) * H + gx) * CIR + oc * 8];
            *(uint4*)&tin[px * 40 + oc * 8] = v;
        }
    }

    bf16x8 wf[9][NT];
    #pragma unroll
    for (int p = 0; p < 9; ++p)
        #pragma unroll
        for (int t = 0; t < NT; ++t)
            wf[p][t] = *(const bf16x8*)&wp[(p * CO + t * 16 + col) * 32 + oct * 8];
    __syncthreads();

    // ---- conv on rows -1..16, cols -1..16 -> t2 (+bias, OOB=-inf) ----
    #pragma unroll
    for (int rr = 0; rr < 5; ++rr) {
        int r1 = wv * 5 + rr - 1;
        if (r1 > 16) r1 = 16;
        #pragma unroll
        for (int g = 0; g < 2; ++g) {
            const int pc = col + (g ? 1 : -1);
            f32x4 acc[NT];
            #pragma unroll
            for (int t = 0; t < NT; ++t) acc[t] = (f32x4){0.f, 0.f, 0.f, 0.f};
            #pragma unroll
            for (int p = 0; p < 9; ++p) {
                const int ky = p / 3, kx = p % 3;
                const bf16x8 b = *(const bf16x8*)&tin[((r1 + ky + 1) * 20 + (pc + kx + 1)) * 40 + oct * 8];
                #pragma unroll
                for (int t = 0; t < NT; ++t)
                    acc[t] = __builtin_amdgcn_mfma_f32_16x16x32_bf16(wf[p][t], b, acc[t], 0, 0, 0);
            }
            const bool valid = (unsigned)(ty0 + r1) < (unsigned)H && (unsigned)(tx0 + pc) < (unsigned)H;
            const int pbase = ((r1 + 1) * 18 + (pc + 1)) * 40;
            #pragma unroll
            for (int t = 0; t < NT; ++t) {
                const float4 bb = *(const float4*)&bias[t * 16 + oct * 4];
                uint2 o = make_uint2(0xFF80FF80u, 0xFF80FF80u);   // -inf pairs
                if (valid) {
                    o.x = pk2(acc[t][0] + bb.x, acc[t][1] + bb.y);
                    o.y = pk2(acc[t][2] + bb.z, acc[t][3] + bb.w);
                }
                *(uint2*)&t2[pbase + t * 16 + oct * 4] = o;
            }
        }
    }
    __syncthreads();

    // ---- maxpool 8x8 out of t2 ----
    const int HP = H >> 1, qy0 = ty0 >> 1, qx0 = tx0 >> 1;
    constexpr int P4 = CO / 4;                 // 4-ch parts per pixel
    for (int i = tid; i < 64 * P4; i += 256) {
        const int px = i / P4, part = i % P4;  // P4 pow2
        const int qy = px >> 3, qx = px & 7;
        float m0 = -FLT_MAX, m1 = -FLT_MAX, m2 = -FLT_MAX, m3 = -FLT_MAX;
        #pragma unroll
        for (int dy = 0; dy < 3; ++dy)
            #pragma unroll
            for (int dx = 0; dx < 3; ++dx) {
                const uint2 v = *(const uint2*)&t2[((qy * 2 + dy) * 18 + (qx * 2 + dx)) * 40 + part * 4];
                m0 = fmaxf(m0, bflo_f(v.x)); m1 = fmaxf(m1, bfhi_f(v.x));
                m2 = fmaxf(m2, bflo_f(v.y)); m3 = fmaxf(m3, bfhi_f(v.y));
            }
        uint2 o;
        o.x = pk2(m0, m1);
        o.y = pk2(m2, m3);
        *(uint2*)&out[(((size_t)n * HP + qy0 + qy) * HP + qx0 + qx) * CO + part * 4] = o;
    }
}

// ---------------------------------------------------------------------------
// Split-K GEMM + reduce (fp32, unchanged)
// ---------------------------------------------------------------------------
__global__ __launch_bounds__(256) void gemm_splitk_k(
    const float* __restrict__ A, const float* __restrict__ B,
    float* __restrict__ partial, int M, int N, int K, int KC)
{
    __shared__ __align__(16) float As[32][65];
    __shared__ __align__(16) float Bs[32][65];
    const int m0 = blockIdx.x * 64, n0 = blockIdx.y * 64;
    const int kbase = blockIdx.z * KC;
    const int tid = threadIdx.x;
    const int tx = tid & 15, ty = tid >> 4;

    float acc[4][4];
    #pragma unroll
    for (int i = 0; i < 4; ++i)
        #pragma unroll
        for (int j = 0; j < 4; ++j) acc[i][j] = 0.f;

    for (int k0 = kbase; k0 < kbase + KC; k0 += 32) {
        for (int i = tid; i < 64 * 32; i += 256) {
            const int m = i >> 5, k = i & 31;
            As[k][m] = A[(size_t)(m0 + m) * K + k0 + k];
        }
        for (int i = tid; i < 64 * 32; i += 256) {
            const int nn = i >> 5, k = i & 31;
            Bs[k][nn] = B[(size_t)(n0 + nn) * K + k0 + k];
        }
        __syncthreads();
        #pragma unroll
        for (int k = 0; k < 32; ++k) {
            const float4 a = *(const float4*)&As[k][ty * 4];
            const float4 b = *(const float4*)&Bs[k][tx * 4];
            acc[0][0] = fmaf(a.x, b.x, acc[0][0]);
            acc[0][1] = fmaf(a.x, b.y, acc[0][1]);
            acc[0][2] = fmaf(a.x, b.z, acc[0][2]);
            acc[0][3] = fmaf(a.x, b.w, acc[0][3]);
            acc[1][0] = fmaf(a.y, b.x, acc[1][0]);
            acc[1][1] = fmaf(a.y, b.y, acc[1][1]);
            acc[1][2] = fmaf(a.y, b.z, acc[1][2]);
            acc[1][3] = fmaf(a.y, b.w, acc[1][3]);
            acc[2][0] = fmaf(a.z, b.x, acc[2][0]);
            acc[2][1] = fmaf(a.z, b.y, acc[2][1]);
            acc[2][2] = fmaf(a.z, b.z, acc[2][2]);
            acc[2][3] = fmaf(a.z, b.w, acc[2][3]);
            acc[3][0] = fmaf(a.w, b.x, acc[3][0]);
            acc[3][1] = fmaf(a.w, b.y, acc[3][1]);
            acc[3][2] = fmaf(a.w, b.z, acc[3][2]);
            acc[3][3] = fmaf(a.w, b.w, acc[3][3]);
        }
        __syncthreads();
    }

    float* pbase = partial + (size_t)blockIdx.z * M * N;
    #pragma unroll
    for (int i = 0; i < 4; ++i) {
        float4 o = make_float4(acc[i][0], acc[i][1], acc[i][2], acc[i][3]);
        *(float4*)&pbase[(size_t)(m0 + ty * 4 + i) * N + n0 + tx * 4] = o;
    }
}

__global__ __launch_bounds__(256) void gemm_reduce_k(
    const float* __restrict__ partial, const float* __restrict__ bias,
    float* __restrict__ out, int MN, int N, int S, int relu)
{
    const int idx = blockIdx.x * 256 + threadIdx.x;
    if (idx >= MN) return;
    float s = bias[idx % N];
    for (int i = 0; i < S; ++i) s += partial[(size_t)i * MN + idx];
    if (relu) s = fmaxf(s, 0.f);
    out[idx] = s;
}

// ---------------------------------------------------------------------------
// CBAM (leading relu): input NHWC bf16, output NCHW fp32  (unchanged)
// ---------------------------------------------------------------------------
__global__ __launch_bounds__(256) void cbam_k(
    const ushort_t* __restrict__ in, const float* __restrict__ fc1,
    const float* __restrict__ fc2, const float* __restrict__ spw,
    float* __restrict__ out)
{
    __shared__ float xl[32][257];
    __shared__ float cmean[32], cmax[32], hidm[8], hidx[8], ca[32];
    __shared__ float spm[256], spx[256], sa[256];
    const int n = blockIdx.x, tid = threadIdx.x;
    const ushort_t* inN = in + (size_t)n * 8192;
    #pragma unroll
    for (int c8 = 0; c8 < 4; ++c8) {
        const uint4 v = *(const uint4*)&inN[tid * 32 + c8 * 8];
        xl[c8 * 8 + 0][tid] = fmaxf(bflo_f(v.x), 0.f);
        xl[c8 * 8 + 1][tid] = fmaxf(bfhi_f(v.x), 0.f);
        xl[c8 * 8 + 2][tid] = fmaxf(bflo_f(v.y), 0.f);
        xl[c8 * 8 + 3][tid] = fmaxf(bfhi_f(v.y), 0.f);
        xl[c8 * 8 + 4][tid] = fmaxf(bflo_f(v.z), 0.f);
        xl[c8 * 8 + 5][tid] = fmaxf(bfhi_f(v.z), 0.f);
        xl[c8 * 8 + 6][tid] = fmaxf(bflo_f(v.w), 0.f);
        xl[c8 * 8 + 7][tid] = fmaxf(bfhi_f(v.w), 0.f);
    }
    __syncthreads();
    if (tid < 32) {
        float s = 0.f, m = -FLT_MAX;
        for (int p = 0; p < 256; ++p) { float v = xl[tid][p]; s += v; m = fmaxf(m, v); }
        cmean[tid] = s * (1.f / 256.f); cmax[tid] = m;
    }
    __syncthreads();
    if (tid < 8) {
        float sm = 0.f, sx = 0.f;
        for (int c = 0; c < 32; ++c) {
            float f = fc1[tid * 32 + c];
            sm += f * cmean[c]; sx += f * cmax[c];
        }
        hidm[tid] = fmaxf(sm, 0.f); hidx[tid] = fmaxf(sx, 0.f);
    }
    __syncthreads();
    if (tid < 32) {
        float s = 0.f;
        for (int h = 0; h < 8; ++h) s += fc2[tid * 8 + h] * (hidm[h] + hidx[h]);
        ca[tid] = 1.f / (1.f + expf(-s));
    }
    __syncthreads();
    {
        float s = 0.f, m = -FLT_MAX;
        for (int c = 0; c < 32; ++c) {
            float v = xl[c][tid] * ca[c];
            xl[c][tid] = v;
            s += v; m = fmaxf(m, v);
        }
        spm[tid] = s * (1.f / 32.f); spx[tid] = m;
    }
    __syncthreads();
    {
        const int y = tid >> 4, x = tid & 15;
        float s = 0.f;
        for (int ky = 0; ky < 7; ++ky) {
            const int yy = y + ky - 3;
            if (yy < 0 || yy >= 16) continue;
            for (int kx = 0; kx < 7; ++kx) {
                const int xx = x + kx - 3;
                if (xx < 0 || xx >= 16) continue;
                const int p = yy * 16 + xx;
                s += spm[p] * spw[ky * 7 + kx] + spx[p] * spw[49 + ky * 7 + kx];
            }
        }
        sa[tid] = 1.f / (1.f + expf(-s));
    }
    __syncthreads();
    float* outN = out + (size_t)n * 8192;
    const float sav = sa[tid];
    for (int c = 0; c < 32; ++c) outN[c * 256 + tid] = xl[c][tid] * sav;
}

// ---------------------------------------------------------------------------
// GRU scan (unchanged)
// ---------------------------------------------------------------------------
__global__ __launch_bounds__(384) void gru_k(
    const float* __restrict__ gi, const float* __restrict__ done,
    const float* __restrict__ h0, const float* __restrict__ whh,
    const float* __restrict__ bhh, float* __restrict__ hidden)
{
    const int b = blockIdx.x, j = threadIdx.x;
    __shared__ __align__(16) float hl[128];
    __shared__ float gh[384];
    float4 wr[32];
    const float4* wrow = (const float4*)(whh + (size_t)j * 128);
    #pragma unroll
    for (int i = 0; i < 32; ++i) wr[i] = wrow[i];
    const float bj = bhh[j];
    if (j < 128) hl[j] = h0[b * 128 + j];
    __syncthreads();
    for (int t = 0; t < 64; ++t) {
        const int rowi = t * 8 + b;
        const float dmask = 1.f - done[rowi];
        if (j < 128) hl[j] *= dmask;
        __syncthreads();
        float s = bj;
        const float4* h4 = (const float4*)hl;
        #pragma unroll
        for (int i = 0; i < 32; ++i) {
            const float4 h = h4[i];
            s = fmaf(wr[i].x, h.x, s);
            s = fmaf(wr[i].y, h.y, s);
            s = fmaf(wr[i].z, h.z, s);
            s = fmaf(wr[i].w, h.w, s);
        }
        gh[j] = s;
        __syncthreads();
        if (j < 128) {
            const float* gir = gi + (size_t)rowi * 384;
            const float r = 1.f / (1.f + expf(-(gir[j] + gh[j])));
            const float z = 1.f / (1.f + expf(-(gir[128 + j] + gh[128 + j])));
            const float nn = tanhf(gir[256 + j] + r * gh[256 + j]);
            const float hm = hl[j];
            const float hn = (1.f - z) * nn + z * hm;
            hl[j] = hn;
            hidden[(size_t)rowi * 128 + j] = hn;
        }
        __syncthreads();
    }
}

// ---------------------------------------------------------------------------
// actor/critic heads (unchanged)
// ---------------------------------------------------------------------------
__global__ __launch_bounds__(256) void heads_k(
    const float* __restrict__ hidden, const float* __restrict__ aw,
    const float* __restrict__ ab, const float* __restrict__ cw,
    const float* __restrict__ cb, float* __restrict__ out)
{
    const int idx = blockIdx.x * 256 + threadIdx.x;  // 2048
    const int m = idx >> 2, c = idx & 3;
    const float* h = hidden + (size_t)m * 128;
    const float* w = (c < 3) ? (aw + (size_t)c * 128) : cw;
    float s = (c < 3) ? ab[c] : cb[0];
    for (int k = 0; k < 128; ++k) s = fmaf(h[k], w[k], s);
    out[idx] = s;
}

// ---------------------------------------------------------------------------
extern "C" void kernel_launch(void* const* d_in, const int* in_sizes, int n_in,
                              void* d_out, int out_size, void* d_ws, size_t ws_size,
                              hipStream_t stream)
{
    const float* x      = (const float*)d_in[0];
    const float* done   = (const float*)d_in[1];
    const float* gstate = (const float*)d_in[2];
    const float* s0_cw  = (const float*)d_in[3];
    const float* s0_cb  = (const float*)d_in[4];
    const float* s0_rw  = (const float*)d_in[5];
    const float* s0_rb  = (const float*)d_in[6];
    const float* s1_cw  = (const float*)d_in[7];
    const float* s1_cb  = (const float*)d_in[8];
    const float* s1_rw  = (const float*)d_in[9];
    const float* s1_rb  = (const float*)d_in[10];
    const float* s2_cw  = (const float*)d_in[11];
    const float* s2_cb  = (const float*)d_in[12];
    const float* s2_rw  = (const float*)d_in[13];
    const float* s2_rb  = (const float*)d_in[14];
    const float* cfc1   = (const float*)d_in[15];
    const float* cfc2   = (const float*)d_in[16];
    const float* cspw   = (const float*)d_in[17];
    const float* fc_w   = (const float*)d_in[18];
    const float* fc_b   = (const float*)d_in[19];
    const float* gwih   = (const float*)d_in[20];
    const float* gwhh   = (const float*)d_in[21];
    const float* gbih   = (const float*)d_in[22];
    const float* gbhh   = (const float*)d_in[23];
    const float* aw     = (const float*)d_in[24];
    const float* ab     = (const float*)d_in[25];
    const float* cwt    = (const float*)d_in[26];
    const float* cbs    = (const float*)d_in[27];
    float* out = (float*)d_out;

    // ---- ws layout (ushort units) ----
    ushort_t* wsu = (ushort_t*)d_ws;
    ushort_t* SCR = wsu;                       // 33,554,432 u (67.1 MB) ping buffer
    ushort_t* U1  = wsu + 33554432;            // 33,554,432 u s0 x
    ushort_t* U3  = wsu + 67108864;            // 16,777,216 u s1 x
    ushort_t* X0  = wsu + 83886080;            //  4,194,304 u s2 x
    ushort_t* WP  = wsu + 88080384;            //    131,072 u weights
    float* CBO   = (float*)SCR;                // 4,194,304 f (after s2 resB done)
    float* PART  = (float*)U1;                 // 4,194,304 f
    float* FEAT  = PART + 4194304;
    float* GI    = FEAT + 131072;
    float* PARTG = GI + 196608;
    float* HID   = PARTG + 786432;

    // ---- prepack all 15 conv weight tensors ----
    ushort_t* wp_s0e = WP;                       // 4608
    ushort_t* wp_s0r = WP + 4608;                // 4 x 4608
    ushort_t* wp_s1e = WP + 23040;               // 9216
    ushort_t* wp_s1r = WP + 32256;               // 4 x 9216
    ushort_t* wp_s2e = WP + 69120;               // 9216
    ushort_t* wp_s2r = WP + 78336;               // 4 x 9216
    {
        PPArgs a;
        a.j[0] = {s0_cw, wp_s0e, 6, 16};
        for (int i = 0; i < 4; ++i) a.j[1 + i] = {s0_rw + i * 2304, wp_s0r + i * 4608, 16, 16};
        a.j[5] = {s1_cw, wp_s1e, 16, 32};
        for (int i = 0; i < 4; ++i) a.j[6 + i] = {s1_rw + i * 9216, wp_s1r + i * 9216, 32, 32};
        a.j[10] = {s2_cw, wp_s2e, 32, 32};
        for (int i = 0; i < 4; ++i) a.j[11 + i] = {s2_rw + i * 9216, wp_s2r + i * 9216, 32, 32};
        prepack_k<<<15, 256, 0, stream>>>(a);
    }

    // ---- stage 0: fused entry conv+pool (6->16 @128 -> @64), one dispatch ----
    convpool_k<6, 16, true><<<dim3(64, 512), 256, 0, stream>>>(x, wp_s0e, s0_cb, U1, 128, 8);
    // ---- stage 0: fused resblocks (16ch @64) ----
    resblock_k<16><<<dim3(16, 512), 256, 0, stream>>>(U1,  wp_s0r + 0 * 4608, wp_s0r + 1 * 4608, s0_rb + 0,  s0_rb + 16, SCR, 64, 4);
    resblock_k<16><<<dim3(16, 512), 256, 0, stream>>>(SCR, wp_s0r + 2 * 4608, wp_s0r + 3 * 4608, s0_rb + 32, s0_rb + 48, U1,  64, 4);
    // ---- stage 1: fused entry conv+pool (16->32 @64 -> @32) ----
    convpool_k<16, 32, false><<<dim3(16, 512), 256, 0, stream>>>(U1, wp_s1e, s1_cb, U3, 64, 4);
    // ---- stage 1: fused resblocks (32ch @32) ----
    resblock_k<32><<<dim3(4, 512), 256, 0, stream>>>(U3,  wp_s1r + 0 * 9216, wp_s1r + 1 * 9216, s1_rb + 0,  s1_rb + 32, SCR, 32, 2);
    resblock_k<32><<<dim3(4, 512), 256, 0, stream>>>(SCR, wp_s1r + 2 * 9216, wp_s1r + 3 * 9216, s1_rb + 64, s1_rb + 96, U3,  32, 2);
    // ---- stage 2: fused entry conv+pool (32->32 @32 -> @16) ----
    convpool_k<32, 32, false><<<dim3(4, 512), 256, 0, stream>>>(U3, wp_s2e, s2_cb, X0, 32, 2);
    // ---- stage 2: fused resblocks (32ch @16) ----
    resblock_k<32><<<dim3(1, 512), 256, 0, stream>>>(X0,  wp_s2r + 0 * 9216, wp_s2r + 1 * 9216, s2_rb + 0,  s2_rb + 32, SCR, 16, 1);
    resblock_k<32><<<dim3(1, 512), 256, 0, stream>>>(SCR, wp_s2r + 2 * 9216, wp_s2r + 3 * 9216, s2_rb + 64, s2_rb + 96, X0,  16, 1);
    // ---- relu + CBAM (NHWC bf16 -> NCHW fp32) ----
    cbam_k<<<512, 256, 0, stream>>>(X0, cfc1, cfc2, cspw, CBO);
    // ---- FC 8192->256 (+relu), split-K=32 ----
    gemm_splitk_k<<<dim3(8, 4, 32), 256, 0, stream>>>(CBO, fc_w, PART, 512, 256, 8192, 256);
    gemm_reduce_k<<<512, 256, 0, stream>>>(PART, fc_b, FEAT, 512 * 256, 256, 32, 1);
    // ---- gi = feat @ Wih^T + bih, split-K=4 ----
    gemm_splitk_k<<<dim3(8, 6, 4), 256, 0, stream>>>(FEAT, gwih, PARTG, 512, 384, 256, 64);
    gemm_reduce_k<<<768, 256, 0, stream>>>(PARTG, gbih, GI, 512 * 384, 384, 4, 0);
    // ---- GRU scan ----
    gru_k<<<8, 384, 0, stream>>>(GI, done, gstate, gwhh, gbhh, HID);
    // ---- heads ----
    heads_k<<<8, 256, 0, stream>>>(HID, aw, ab, cwt, cbs, out);
}